// Round 1
// baseline (118.810 us; speedup 1.0000x reference)
//
#include <hip/hip_runtime.h>

// Problem constants (B*H*W = 64*32*32 = 65536 vectors of dim 64, 512 codes)
#define NVEC 65536
#define DIM 64
#define KCODES 512

// Block: 256 threads = 4 waves. Waves 0,1 handle 128 vectors with k in [0,256);
// waves 2,3 handle the SAME 128 vectors with k in [256,512). Merge via LDS.
// Grid: NVEC/128 = 512 blocks -> 2 blocks/CU, 2 waves/SIMD.
__global__ __launch_bounds__(256, 2) void vq_kernel(const float* __restrict__ x,
                                                    const float* __restrict__ emb,
                                                    float* __restrict__ out,
                                                    float* __restrict__ ws,
                                                    int nblocks) {
    __shared__ float en[KCODES];     // ||e_k||^2
    __shared__ float sdist[128];
    __shared__ int   sidx[128];
    __shared__ float swl[4];

    const int tid = threadIdx.x;

    // --- codebook norms (coalesced over k) ---
    for (int kk = tid; kk < KCODES; kk += 256) {
        float s = 0.f;
#pragma unroll
        for (int d = 0; d < DIM; ++d) {
            float v = emb[d * KCODES + kk];
            s = fmaf(v, v, s);
        }
        en[kk] = s;
    }
    __syncthreads();

    const int wid  = tid >> 6;
    const int lane = tid & 63;
    // force wave-uniform k-half into SGPR so embedding addresses scalarize
    const int khalf    = __builtin_amdgcn_readfirstlane(wid >> 1);
    const int vecLocal = ((wid & 1) << 6) + lane;
    const int vec      = blockIdx.x * 128 + vecLocal;

    // --- load z into registers ---
    float z[DIM];
#pragma unroll
    for (int d = 0; d < DIM; d += 4) {
        float4 v = *reinterpret_cast<const float4*>(x + (size_t)vec * DIM + d);
        z[d] = v.x; z[d + 1] = v.y; z[d + 2] = v.z; z[d + 3] = v.w;
    }
    float znorm = 0.f;
#pragma unroll
    for (int d = 0; d < DIM; ++d) znorm = fmaf(z[d], z[d], znorm);

    // --- scan 256 codes (this wave's half), 8 codes per tile ---
    float best  = 3.4e38f;
    int   bestk = 0;
    const int kbase0 = khalf * 256;
    for (int kt = 0; kt < 32; ++kt) {
        const int kbase = kbase0 + kt * 8;
        float acc[8] = {0.f, 0.f, 0.f, 0.f, 0.f, 0.f, 0.f, 0.f};
#pragma unroll
        for (int d = 0; d < DIM; ++d) {
            const float* ep = emb + d * KCODES + kbase;  // wave-uniform -> s_load
#pragma unroll
            for (int j = 0; j < 8; ++j) acc[j] = fmaf(z[d], ep[j], acc[j]);
        }
#pragma unroll
        for (int j = 0; j < 8; ++j) {
            // match reference association: (||z||^2 + ||e||^2) - 2*dot
            float t    = znorm + en[kbase + j];
            float dist = t - 2.0f * acc[j];
            if (dist < best) { best = dist; bestk = kbase + j; }  // first-min wins
        }
    }

    // --- merge halves: waves 2,3 post to LDS, waves 0,1 finalize ---
    if (khalf == 1) { sdist[vecLocal] = best; sidx[vecLocal] = bestk; }
    __syncthreads();

    float lossLocal = 0.f;
    if (khalf == 0) {
        float d2 = sdist[vecLocal];
        int   i2 = sidx[vecLocal];
        // tie -> lower index (khalf0 indices are smaller, so strict < suffices)
        if (d2 < best) { best = d2; bestk = i2; }
        // gather chosen code, write output, accumulate loss
#pragma unroll
        for (int d = 0; d < DIM; d += 4) {
            float4 q;
            q.x = emb[(d + 0) * KCODES + bestk];
            q.y = emb[(d + 1) * KCODES + bestk];
            q.z = emb[(d + 2) * KCODES + bestk];
            q.w = emb[(d + 3) * KCODES + bestk];
            *reinterpret_cast<float4*>(out + (size_t)vec * DIM + d) = q;
            float a0 = q.x - z[d];
            float a1 = q.y - z[d + 1];
            float a2 = q.z - z[d + 2];
            float a3 = q.w - z[d + 3];
            lossLocal += a0 * a0 + a1 * a1 + a2 * a2 + a3 * a3;
        }
    }

    // --- block-reduce loss, atomic accumulate, last block finalizes ---
#pragma unroll
    for (int off = 32; off; off >>= 1) lossLocal += __shfl_down(lossLocal, off, 64);
    if (lane == 0) swl[wid] = lossLocal;
    __syncthreads();
    if (tid == 0) {
        float s = swl[0] + swl[1] + swl[2] + swl[3];
        atomicAdd(&ws[0], s);
        __threadfence();
        unsigned int* cnt = reinterpret_cast<unsigned int*>(ws + 1);
        unsigned int prev = atomicAdd(cnt, 1u);
        if (prev == (unsigned int)(nblocks - 1)) {
            float total = atomicAdd(&ws[0], 0.0f);  // coherent read of final sum
            out[(size_t)NVEC * DIM] = 2.0f * total / (float)((size_t)NVEC * DIM);
        }
    }
}

extern "C" void kernel_launch(void* const* d_in, const int* in_sizes, int n_in,
                              void* d_out, int out_size, void* d_ws, size_t ws_size,
                              hipStream_t stream) {
    const float* x   = (const float*)d_in[0];
    const float* emb = (const float*)d_in[1];
    float* out = (float*)d_out;
    float* ws  = (float*)d_ws;

    // zero loss accumulator + block counter (capture-safe async memset)
    hipMemsetAsync(d_ws, 0, 8, stream);

    const int nblocks = NVEC / 128;  // 512
    vq_kernel<<<dim3(nblocks), dim3(256), 0, stream>>>(x, emb, out, ws, nblocks);
}